// Round 3
// baseline (747.497 us; speedup 1.0000x reference)
//
#include <hip/hip_runtime.h>
#include <hip/hip_bf16.h>

// Banded-Gram bf16 MFMA formulation.
// out[b, dy*9+dx, h, w] = (1/256) sum_c in1[b,c,h,w] * in2[b,c,h+dy-4,w+dx-4]
// Per block (b, h, w-half): GEMM tiles D = A·B, A = in1 pixels(16) x K=32ch,
// B = in2 staged cols(80: w0h-4..w0h+75, rows h-4..h+4) x K. Band density 28%
// of the 16x32 D-tiles is used; MFMA is ~15x faster than the vector path so
// this wins despite the waste. Staged zeros implement the zero-padding.
//
// LDS (62720 B, one char array):
//   staging: col 0..719 = in2 (r*80+qi), col 720..783 = in1 px; each col =
//   32 bf16 k + 8 pad halfs (80 B stride -> 2-way-free b128 frag reads)
//   epilogue (after barrier, overlaid): per-wave 16x33 fp32 transpose tile

#define CH 256
#define HH 96
#define WW 128
#define CS (HH * WW)

typedef __bf16 bf16x8 __attribute__((ext_vector_type(8)));
typedef float  f32x4  __attribute__((ext_vector_type(4)));

__device__ inline uint2 pk4(float a, float b, float c, float d) {
  union { __hip_bfloat162 h; unsigned u; } x, y;
  x.h = __float22bfloat162_rn(make_float2(a, b));
  y.h = __float22bfloat162_rn(make_float2(c, d));
  return make_uint2(x.u, y.u);
}

__global__ __launch_bounds__(256) void corr_mfma(
    const float* __restrict__ in1, const float* __restrict__ in2,
    float* __restrict__ out)
{
  __shared__ __align__(16) char smem[784 * 80];  // 62720 B

  // ---- block decode: xcd-swizzled h so neighboring-h blocks share an XCD L2
  const int bid  = blockIdx.x;
  const int xcd  = bid & 7;
  const int idx  = bid >> 3;       // 0..191
  const int hh   = idx % 12;
  const int rest = idx / 12;       // 0..15
  const int b    = rest & 7;
  const int wh   = rest >> 3;
  const int h    = xcd * 12 + hh;  // 0..95
  const int w0h  = wh * 64;

  const int tid  = threadIdx.x;
  const int lane = tid & 63;
  const int wv   = tid >> 6;       // wave id = A-tile (16 px)
  const int m    = lane & 15;      // MFMA m / n index
  const int quad = lane >> 4;      // MFMA k-quad

  const float* __restrict__ in1b = in1 + (size_t)b * CH * CS;
  const float* __restrict__ in2b = in2 + (size_t)b * CH * CS;

  // ---- staging task precompute (per thread, loop-invariant) ----
  // cols 0..719: in2, col = r*80+qi -> (row h-4+r, col w0h-4+qi), zero if OOB
  // cols 720..783: in1, px = col-720 -> (row h, col w0h+px)
  int vo0, vo1, vo2 = 0, voA = 0;
  bool ok0, ok1, ok2 = false;
  int lb0, lb1, lb2 = 0, lbA = 0;
  {
    int col = tid;                       // j0: always in2
    int r = col / 80, qi = col - r * 80;
    int gr = h - 4 + r, gc = w0h - 4 + qi;
    ok0 = (unsigned)gr < (unsigned)HH && (unsigned)gc < (unsigned)WW;
    vo0 = ok0 ? gr * WW + gc : 0;
    lb0 = col * 80;
  }
  {
    int col = tid + 256;                 // j1: always in2
    int r = col / 80, qi = col - r * 80;
    int gr = h - 4 + r, gc = w0h - 4 + qi;
    ok1 = (unsigned)gr < (unsigned)HH && (unsigned)gc < (unsigned)WW;
    vo1 = ok1 ? gr * WW + gc : 0;
    lb1 = col * 80;
  }
  if (tid < 208) {                       // j2: in2 for tid<208
    int col = tid + 512;
    int r = col / 80, qi = col - r * 80;
    int gr = h - 4 + r, gc = w0h - 4 + qi;
    ok2 = (unsigned)gr < (unsigned)HH && (unsigned)gc < (unsigned)WW;
    vo2 = ok2 ? gr * WW + gc : 0;
    lb2 = col * 80;
  } else {                               // j2: in1 px 0..47
    int px = tid - 208;
    voA = h * WW + w0h + px;
    lbA = (720 + px) * 80;
  }
  if (tid < 16) {                        // j3: in1 px 48..63
    int px = 48 + tid;
    voA = h * WW + w0h + px;
    lbA = (720 + px) * 80;
  }

  f32x4 acc[9][2];
#pragma unroll
  for (int dy = 0; dy < 9; ++dy)
#pragma unroll
    for (int t = 0; t < 2; ++t)
      acc[dy][t] = (f32x4){0.f, 0.f, 0.f, 0.f};

  // ---- K loop: 8 chunks of 32 channels ----
  for (int c0 = 0; c0 < CH; c0 += 32) {
    // stage: fp32 global -> bf16 LDS (k-contiguous per col)
#pragma unroll
    for (int kq = 0; kq < 8; ++kq) {
      const float* b2 = in2b + (size_t)(c0 + kq * 4) * CS;  // uniform base
      const float* b1 = in1b + (size_t)(c0 + kq * 4) * CS;
      {
        float v0 = 0.f, v1 = 0.f, v2 = 0.f, v3 = 0.f;
        if (ok0) { v0 = b2[vo0]; v1 = b2[vo0 + CS]; v2 = b2[vo0 + 2 * CS]; v3 = b2[vo0 + 3 * CS]; }
        *(uint2*)(smem + lb0 + kq * 8) = pk4(v0, v1, v2, v3);
      }
      {
        float v0 = 0.f, v1 = 0.f, v2 = 0.f, v3 = 0.f;
        if (ok1) { v0 = b2[vo1]; v1 = b2[vo1 + CS]; v2 = b2[vo1 + 2 * CS]; v3 = b2[vo1 + 3 * CS]; }
        *(uint2*)(smem + lb1 + kq * 8) = pk4(v0, v1, v2, v3);
      }
      if (tid < 208) {
        float v0 = 0.f, v1 = 0.f, v2 = 0.f, v3 = 0.f;
        if (ok2) { v0 = b2[vo2]; v1 = b2[vo2 + CS]; v2 = b2[vo2 + 2 * CS]; v3 = b2[vo2 + 3 * CS]; }
        *(uint2*)(smem + lb2 + kq * 8) = pk4(v0, v1, v2, v3);
      } else {
        float v0 = b1[voA], v1 = b1[voA + CS], v2 = b1[voA + 2 * CS], v3 = b1[voA + 3 * CS];
        *(uint2*)(smem + lbA + kq * 8) = pk4(v0, v1, v2, v3);
      }
      if (tid < 16) {
        float v0 = b1[voA], v1 = b1[voA + CS], v2 = b1[voA + 2 * CS], v3 = b1[voA + 3 * CS];
        *(uint2*)(smem + lbA + kq * 8) = pk4(v0, v1, v2, v3);
      }
    }
    __syncthreads();

    // compute: A-frag [m=lane&15][k=quad*8+j]; B-frag col n=lane&15, same k
    bf16x8 af = *(const bf16x8*)(smem + (720 + wv * 16 + m) * 80 + quad * 16);
#pragma unroll
    for (int dy = 0; dy < 9; ++dy) {
#pragma unroll
      for (int t = 0; t < 2; ++t) {
        bf16x8 bf = *(const bf16x8*)(
            smem + (dy * 80 + wv * 16 + t * 16 + m) * 80 + quad * 16);
        acc[dy][t] = __builtin_amdgcn_mfma_f32_16x16x32_bf16(af, bf, acc[dy][t], 0, 0, 0);
      }
    }
    __syncthreads();
  }

  // ---- epilogue: per-wave LDS transpose of the banded tiles, coalesced store
  __syncthreads();  // staging区 dead; overlay per-wave fp32 transpose tiles
  float* ep = (float*)smem + wv * 528;   // 16 rows x 33 (pad) floats
  const float sc = 1.0f / (float)CH;
#pragma unroll 1
  for (int dy = 0; dy < 9; ++dy) {
    // scatter D-frags: D row = quad*4+reg (pixel), col = t*16 + (lane&15)
#pragma unroll
    for (int t = 0; t < 2; ++t)
#pragma unroll
      for (int r = 0; r < 4; ++r)
        ep[(quad * 4 + r) * 33 + t * 16 + m] = acc[dy][t][r];
    // gather band: u = lane+64s -> (dx = u>>4, p = u&15); col index = p+dx
#pragma unroll
    for (int s = 0; s < 3; ++s) {
      int u = lane + 64 * s;
      if (u < 144) {
        int dx = u >> 4, p = u & 15;
        float v = ep[p * 33 + p + dx] * sc;
        out[(((size_t)b * 81 + dy * 9 + dx) * HH + h) * WW + w0h + wv * 16 + p] = v;
      }
    }
    __syncthreads();  // ep region reused next dy by same wave; cheap, safe
  }
}

extern "C" void kernel_launch(void* const* d_in, const int* in_sizes, int n_in,
                              void* d_out, int out_size, void* d_ws, size_t ws_size,
                              hipStream_t stream) {
  const float* in1 = (const float*)d_in[0];
  const float* in2 = (const float*)d_in[1];
  float* out = (float*)d_out;
  hipLaunchKernelGGL(corr_mfma, dim3(1536), dim3(256), 0, stream, in1, in2, out);
}

// Round 4
// 334.790 us; speedup vs baseline: 2.2327x; 2.2327x over previous
//
#include <hip/hip_runtime.h>

// Local cost-volume correlation, fp32 vector path, DPP window sharing.
// out[b, dy*9+dx, h, w] = (1/256) sum_c in1[b,c,h,w] * in2[b,c,h+dy-4,w+dx-4]
//
// R4 design (from R2 post-mortem: latency+L1-bound, 4 dep loads/iter):
//  - wave = 2 full image rows (lane = r*32+g), 4 px/lane, one dy per block
//  - per channel: 2 coalesced float4 loads (in1 px, in2 px at clamped row);
//    left/right window float4s come from lane g-1 / g+1 via DPP wave_shr:1 /
//    wave_shl:1 (VALU, no LDS pipe, no extra L1 traffic)
//  - zero in-loop masking: kernel_size==1 means every (p,dx) output reads ONE
//    in2 element; OOB row/col => output is exactly 0 => garbage (DPP wave-
//    boundary wrap, clamped-row data) is zeroed branch-free at the store
//  - XCD swizzle: 9 dy-blocks of a tile share blockIdx%8 (L2/L3 reuse, R2-proven)

#define CH 256
#define HH 96
#define WW 128
#define CS (HH * WW)

__device__ __forceinline__ float wshr1(float x) {  // lane i <- lane i-1
  union { float f; int i; } u, o;
  u.f = x;
  o.i = __builtin_amdgcn_update_dpp(0, u.i, 0x138, 0xF, 0xF, true);
  return o.f;
}
__device__ __forceinline__ float wshl1(float x) {  // lane i <- lane i+1
  union { float f; int i; } u, o;
  u.f = x;
  o.i = __builtin_amdgcn_update_dpp(0, u.i, 0x130, 0xF, 0xF, true);
  return o.f;
}

__global__ __launch_bounds__(256, 4) void corr_dpp(
    const float* __restrict__ in1, const float* __restrict__ in2,
    float* __restrict__ out)
{
  // ---- block decode, XCD-swizzled: tile's 9 dy-blocks share blockIdx%8 ----
  const int j    = blockIdx.x;          // grid = 864
  const int xcd  = j & 7;
  const int s    = j >> 3;              // 0..107
  const int dy   = s % 9;
  const int tq   = s / 9;               // 0..11
  const int tile = tq * 8 + xcd;        // 0..95
  const int band = tile % 12;
  const int b    = tile / 12;
  const int dyo  = dy - 4;

  // ---- thread decode: 4 waves x (2 rows x 32 col-groups), 4 px/lane ----
  const int tid  = threadIdx.x;
  const int wv   = tid >> 6;
  const int lane = tid & 63;
  const int r    = lane >> 5;
  const int g    = lane & 31;
  const int h    = band * 8 + wv * 2 + r;   // 0..95, always valid
  const int px   = g << 2;                  // 0..124
  const int r2   = h + dyo;                 // in2 row, may be OOB
  const bool rowok = (unsigned)r2 < (unsigned)HH;
  const int r2c  = r2 < 0 ? 0 : (r2 > HH - 1 ? HH - 1 : r2);

  const float* p1 = in1 + ((size_t)b * CH * HH + h)   * WW + px;
  const float* p2 = in2 + ((size_t)b * CH * HH + r2c) * WW + px;

  float acc[4][9];
#pragma unroll
  for (int p = 0; p < 4; ++p)
#pragma unroll
    for (int d = 0; d < 9; ++d) acc[p][d] = 0.f;

#pragma unroll 2
  for (int c = 0; c < CH; ++c) {
    float4 a4 = *(const float4*)p1;  p1 += CS;
    float4 m4 = *(const float4*)p2;  p2 += CS;

    // window w[0..11] = in2 cols px-4 .. px+7 (same row), via DPP neighbors
    float w[12];
    w[0] = wshr1(m4.x); w[1] = wshr1(m4.y); w[2] = wshr1(m4.z); w[3] = wshr1(m4.w);
    w[4] = m4.x; w[5] = m4.y; w[6] = m4.z; w[7] = m4.w;
    w[8] = wshl1(m4.x); w[9] = wshl1(m4.y); w[10] = wshl1(m4.z); w[11] = wshl1(m4.w);

    const float av[4] = {a4.x, a4.y, a4.z, a4.w};
#pragma unroll
    for (int p = 0; p < 4; ++p)
#pragma unroll
      for (int d = 0; d < 9; ++d)
        acc[p][d] = fmaf(av[p], w[p + d], acc[p][d]);
  }

  // ---- epilogue: zero OOB (row + col) contributions, scale, float4 store ----
  const float sc = 1.0f / (float)CH;
  float* po = out + (((size_t)b * 81 + dy * 9) * HH + h) * WW + px;
#pragma unroll
  for (int d = 0; d < 9; ++d) {
    float v[4];
#pragma unroll
    for (int p = 0; p < 4; ++p) {
      const int col2 = px + p + d - 4;                       // in2 column
      const bool ok  = rowok && ((unsigned)col2 < (unsigned)WW);
      v[p] = ok ? acc[p][d] * sc : 0.f;
    }
    *(float4*)po = make_float4(v[0], v[1], v[2], v[3]);
    po += (size_t)CS;  // next (dy,dx) plane
  }
}

extern "C" void kernel_launch(void* const* d_in, const int* in_sizes, int n_in,
                              void* d_out, int out_size, void* d_ws, size_t ws_size,
                              hipStream_t stream) {
  const float* in1 = (const float*)d_in[0];
  const float* in2 = (const float*)d_in[1];
  float* out = (float*)d_out;
  hipLaunchKernelGGL(corr_dpp, dim3(864), dim3(256), 0, stream, in1, in2, out);
}